// Round 17
// baseline (313.837 us; speedup 1.0000x reference)
//
#include <hip/hip_runtime.h>

// Problem constants (match reference)
#define NV 100000
#define NE 400000
#define BB 4
#define NSUB 10
constexpr float DT        = 0.01f;
constexpr float K_SPRING  = 1000.0f;
constexpr float DAMP      = 0.999f;
constexpr float ACT_SCALE = 0.1f;
constexpr float EPS       = 1e-6f;

#define VEL_BASE ((size_t)BB * (NSUB + 1) * NV * 3)
#define NBLK ((NV + 255) / 256)        // 391 blocks for per-node arrays
#define PADCAP (2 * NE + 3 * NV + 64)  // padded slot capacity

typedef float fv4 __attribute__((ext_vector_type(4)));
typedef int   iv4 __attribute__((ext_vector_type(4)));

// ---------- one-time setup ----------

// Merged: one thread per gid < BB*NV does state init for (v = gid>>2, b = gid&3)
// AND degree-count for edge gid (BB*NV == NE here; guard anyway).
__global__ void init_count(const float* __restrict__ pos0,
                           const float* __restrict__ vel0,
                           const int2* __restrict__ edges,
                           float* __restrict__ out,
                           float4* __restrict__ posT,
                           float4* __restrict__ velT,
                           int* __restrict__ deg) {
    int gid = blockIdx.x * blockDim.x + threadIdx.x;
    if (gid < BB * NV) {
        int b = gid & 3, v = gid >> 2;
        const float* ps = pos0 + ((size_t)b * NV + v) * 3;
        const float* vs = vel0 + ((size_t)b * NV + v) * 3;
        float px = ps[0], py = ps[1], pz = ps[2];
        float vx = vs[0], vy = vs[1], vz = vs[2];
        posT[gid] = make_float4(px, py, pz, 0.f);
        if (velT) velT[gid] = make_float4(vx, vy, vz, 0.f);
        size_t o = ((size_t)(b * (NSUB + 1)) * NV + v) * 3;   // slot 0
        out[o + 0] = px; out[o + 1] = py; out[o + 2] = pz;
        out[VEL_BASE + o + 0] = vx; out[VEL_BASE + o + 1] = vy; out[VEL_BASE + o + 2] = vz;
    }
    if (gid < NE) {
        int2 ed = edges[gid];
        atomicAdd(&deg[ed.x], 1);
        atomicAdd(&deg[ed.y], 1);
    }
}

__global__ void zero_deg(int* __restrict__ deg) {
    int v = blockIdx.x * blockDim.x + threadIdx.x;
    if (v < NV) deg[v] = 0;
}

// --- 3-phase exclusive scan over PADDED degrees -> offs[NV+1] (+cursor) ---
__device__ __forceinline__ int padded(int d) { return (d + 3) & ~3; }

__global__ void scan_partials(const int* __restrict__ deg, int* __restrict__ bsum) {
    __shared__ int red[256];
    int i = blockIdx.x * 256 + threadIdx.x;
    red[threadIdx.x] = (i < NV) ? padded(deg[i]) : 0;
    __syncthreads();
    for (int off = 128; off > 0; off >>= 1) {
        if (threadIdx.x < off) red[threadIdx.x] += red[threadIdx.x + off];
        __syncthreads();
    }
    if (threadIdx.x == 0) bsum[blockIdx.x] = red[0];
}

__global__ void scan_bsums(int* __restrict__ bsum) {   // NBLK <= 512
    __shared__ int s[512];
    int t = threadIdx.x;
    s[t] = (t < NBLK) ? bsum[t] : 0;
    __syncthreads();
    for (int off = 1; off < 512; off <<= 1) {
        int v = (t >= off) ? s[t - off] : 0;
        __syncthreads();
        s[t] += v;
        __syncthreads();
    }
    if (t < NBLK) bsum[t] = (t == 0) ? 0 : s[t - 1];   // exclusive
}

// writes offs/cursor; pads tail slots with zero-contribution self-edges.
__global__ void scan_write(const int* __restrict__ deg, const int* __restrict__ bsum,
                           int* __restrict__ offs, int* __restrict__ cursor,
                           int* __restrict__ lo, float* __restrict__ lre2) {
    __shared__ int s[256];
    int i = blockIdx.x * 256 + threadIdx.x;
    int draw = (i < NV) ? deg[i] : 0;
    int d = padded(draw);
    s[threadIdx.x] = d;
    __syncthreads();
    for (int off = 1; off < 256; off <<= 1) {          // inclusive scan
        int v = (threadIdx.x >= off) ? s[threadIdx.x - off] : 0;
        __syncthreads();
        s[threadIdx.x] += v;
        __syncthreads();
    }
    if (i <= NV - 1) {
        int excl = bsum[blockIdx.x] + s[threadIdx.x] - d;
        offs[i] = excl; cursor[i] = excl;
        if (i == NV - 1) offs[NV] = excl + d;
        for (int k = excl + draw; k < excl + d; ++k) {
            lo[k] = i;
            size_t kb = (size_t)(k & ~3) * 4 + (k & 3);
            #pragma unroll
            for (int b = 0; b < BB; ++b) lre2[kb + 4 * b] = 0.f;
        }
    }
}

// ---------- adjacency fill (single-pass; measured cheaper than two-phase) ----------
// lo[k] = other node.
// lre2 chunk-transposed: lre2[(k&~3)*4 + b*4 + (k&3)] = K_SPRING * rest_eff[b]
__global__ void fill_fat(const int2* __restrict__ edges,
                         const float* __restrict__ action,
                         const float* __restrict__ rest_len,
                         int* __restrict__ cursor,
                         int* __restrict__ lo,
                         float* __restrict__ lre2) {
    int e = blockIdx.x * blockDim.x + threadIdx.x;
    if (e >= NE) return;
    int2 ed = edges[e];
    float krl = K_SPRING * rest_len[e];
    fv4 re;
    #pragma unroll
    for (int b = 0; b < BB; ++b)
        re[b] = krl * (1.0f + ACT_SCALE * tanhf(action[b * NE + e]));
    int p = atomicAdd(&cursor[ed.x], 1);
    int q = atomicAdd(&cursor[ed.y], 1);
    lo[p] = ed.y; lo[q] = ed.x;
    size_t pb = (size_t)(p & ~3) * 4 + (p & 3);
    size_t qb = (size_t)(q & ~3) * 4 + (q & 3);
    #pragma unroll
    for (int b = 0; b < BB; ++b) {
        lre2[pb + 4 * b] = re[b];
        lre2[qb + 4 * b] = re[b];
    }
}

// ---------- per-substep fused gather + integrate (2-way k-split; best measured) ----------
// Thread gid -> (v = gid>>3, h = (gid>>2)&1, b = gid&3). Lanes of one (v,h)
// cover b=0..3 so each neighbor gather is one fully-used 64B line. Each half
// h processes half the node's 4-chunks; halves combine via __shfl_xor(.,4)
// and lane h==0 integrates.
// Lists (lo/lre2) are CACHED loads (re-read 10x; NT loads cost 10x HBM —
// round-13/14 lesson). Trajectory stores are PLAIN cached stores: NT dword
// stores at 12B/lane stride write-through per-instruction at line granularity
// -> ~3-4x write amplification (round-12 lesson applied to the write path);
// cached stores let L2 write-back coalesce to full lines (round-3 baseline
// measured WRITE_SIZE == ideal with cached stores).
// coef = K*(len-re)/len == K - (K*re)*rsqrt(d2+EPS); lre2 holds K*re.
template <bool VELT>
__global__ void substep_ks(float* __restrict__ out,
                           const float4* __restrict__ posT,
                           float4* __restrict__ posTn,
                           float4* __restrict__ velT,   // thread-owned slot
                           const int* __restrict__ lo,
                           const float* __restrict__ lre2,
                           const int* __restrict__ offs, int s) {
    int gid = blockIdx.x * blockDim.x + threadIdx.x;
    if (gid >= 2 * BB * NV) return;
    int b = gid & 3, h = (gid >> 2) & 1, v = gid >> 3;

    float4 p = posT[v * 4 + b];
    float fx = 0.f, fy = 0.f, fz = 0.f;

    int start = offs[v], end = offs[v + 1];
    int nc0 = ((((end - start) >> 2) + 1) >> 1) << 2;   // first-half slot count
    int k    = h ? (start + nc0) : start;
    int kend = h ? end : (start + nc0);

#define ACC(q, kre) do { \
        float dx = (q).x - p.x, dy = (q).y - p.y, dz = (q).z - p.z; \
        float d2 = fmaf(dx, dx, fmaf(dy, dy, fmaf(dz, dz, EPS))); \
        float rs = rsqrtf(d2); \
        float t  = fmaf(-(kre), rs, K_SPRING); \
        fx = fmaf(t, dx, fx); fy = fmaf(t, dy, fy); fz = fmaf(t, dz, fz); } while (0)

    for (; k + 7 < kend; k += 8) {
        iv4 oA = *(const iv4*)(lo + k);
        iv4 oB = *(const iv4*)(lo + k + 4);
        fv4 rA = *(const fv4*)(lre2 + 4 * (size_t)k + 4 * b);
        fv4 rB = *(const fv4*)(lre2 + 4 * (size_t)(k + 4) + 4 * b);
        float4 qA0 = posT[oA.x * 4 + b];
        float4 qA1 = posT[oA.y * 4 + b];
        float4 qA2 = posT[oA.z * 4 + b];
        float4 qA3 = posT[oA.w * 4 + b];
        float4 qB0 = posT[oB.x * 4 + b];
        float4 qB1 = posT[oB.y * 4 + b];
        float4 qB2 = posT[oB.z * 4 + b];
        float4 qB3 = posT[oB.w * 4 + b];
        ACC(qA0, rA[0]); ACC(qA1, rA[1]); ACC(qA2, rA[2]); ACC(qA3, rA[3]);
        ACC(qB0, rB[0]); ACC(qB1, rB[1]); ACC(qB2, rB[2]); ACC(qB3, rB[3]);
    }
    if (k < kend) {   // one remaining 4-chunk
        iv4 o = *(const iv4*)(lo + k);
        fv4 r = *(const fv4*)(lre2 + 4 * (size_t)k + 4 * b);
        float4 q0 = posT[o.x * 4 + b];
        float4 q1 = posT[o.y * 4 + b];
        float4 q2 = posT[o.z * 4 + b];
        float4 q3 = posT[o.w * 4 + b];
        ACC(q0, r[0]); ACC(q1, r[1]); ACC(q2, r[2]); ACC(q3, r[3]);
    }
#undef ACC

    // combine the two halves (lane ^ 4 flips h)
    fx += __shfl_xor(fx, 4);
    fy += __shfl_xor(fy, 4);
    fz += __shfl_xor(fz, 4);

    if (h == 0) {
        int tg = v * 4 + b;   // (v,b) slot in posT/velT
        size_t cur = ((size_t)(b * (NSUB + 1) + s)) * NV * 3 + (size_t)v * 3;
        size_t nxt = cur + (size_t)NV * 3;

        float vcx, vcy, vcz;
        if (VELT) {
            float4 vc = velT[tg];
            vcx = vc.x; vcy = vc.y; vcz = vc.z;
        } else {
            vcx = out[VEL_BASE + cur + 0];
            vcy = out[VEL_BASE + cur + 1];
            vcz = out[VEL_BASE + cur + 2];
        }
        float vx = (vcx + DT * fx) * DAMP;
        float vy = (vcy + DT * (fy - 9.8f)) * DAMP;
        float vz = (vcz + DT * fz) * DAMP;
        float pxn = p.x + DT * vx, pyn = p.y + DT * vy, pzn = p.z + DT * vz;

        out[nxt + 0] = pxn; out[nxt + 1] = pyn; out[nxt + 2] = pzn;
        out[VEL_BASE + nxt + 0] = vx;
        out[VEL_BASE + nxt + 1] = vy;
        out[VEL_BASE + nxt + 2] = vz;
        if (VELT) velT[tg] = make_float4(vx, vy, vz, 0.f);
        posTn[tg] = make_float4(pxn, pyn, pzn, 0.f);
    }
}

extern "C" void kernel_launch(void* const* d_in, const int* in_sizes, int n_in,
                              void* d_out, int out_size, void* d_ws, size_t ws_size,
                              hipStream_t stream) {
    const float* action   = (const float*)d_in[0];
    const float* pos0     = (const float*)d_in[1];
    const float* vel0     = (const float*)d_in[2];
    const float* rest_len = (const float*)d_in[3];
    const int2*  edges    = (const int2*)d_in[4];
    float* out = (float*)d_out;

    // workspace layout
    char* ws = (char*)d_ws;
    size_t off = 0;
    int* deg    = (int*)(ws + off); off += (size_t)NV * 4;
    int* offs   = (int*)(ws + off); off += (size_t)(NV + 1) * 4;
    int* cursor = (int*)(ws + off); off += (size_t)NV * 4;
    int* bsum   = (int*)(ws + off); off += (size_t)(NBLK + 4) * 4;
    off = (off + 63) & ~(size_t)63;
    float4* pTa = (float4*)(ws + off); off += (size_t)NV * BB * 16;  // 6.4 MB
    float4* pTb = (float4*)(ws + off); off += (size_t)NV * BB * 16;  // 6.4 MB
    int*   lo   = (int*)(ws + off);   off += (size_t)PADCAP * 4;     // 4.4 MB
    float* lre2 = (float*)(ws + off); off += (size_t)PADCAP * 16;    // 17.6 MB
    float4* vT = (float4*)(ws + off);
    const bool velt = ws_size >= off + (size_t)NV * BB * 16;         // +6.4 MB -> ~42.5 MB total

    const int nBV = BB * NV;
    const int nKS = 2 * BB * NV;   // 2-way k-split thread count
    const int nIC = (nBV > NE ? nBV : NE);

    zero_deg<<<NBLK, 256, 0, stream>>>(deg);
    init_count<<<(nIC + 255) / 256, 256, 0, stream>>>(pos0, vel0, edges, out, pTa,
                                                      velt ? vT : nullptr, deg);
    scan_partials<<<NBLK, 256, 0, stream>>>(deg, bsum);
    scan_bsums<<<1, 512, 0, stream>>>(bsum);
    scan_write<<<NBLK, 256, 0, stream>>>(deg, bsum, offs, cursor, lo, lre2);
    fill_fat<<<(NE + 255) / 256, 256, 0, stream>>>(edges, action, rest_len, cursor, lo, lre2);

    for (int s = 0; s < NSUB; ++s) {
        float4* pc = (s & 1) ? pTb : pTa;
        float4* pn = (s & 1) ? pTa : pTb;
        if (velt) {
            substep_ks<true><<<(nKS + 255) / 256, 256, 0, stream>>>(
                out, pc, pn, vT, lo, lre2, offs, s);
        } else {
            substep_ks<false><<<(nKS + 255) / 256, 256, 0, stream>>>(
                out, pc, pn, nullptr, lo, lre2, offs, s);
        }
    }
}

// Round 18
// 289.493 us; speedup vs baseline: 1.0841x; 1.0841x over previous
//
#include <hip/hip_runtime.h>

// Problem constants (match reference)
#define NV 100000
#define NE 400000
#define BB 4
#define NSUB 10
constexpr float DT        = 0.01f;
constexpr float K_SPRING  = 1000.0f;
constexpr float DAMP      = 0.999f;
constexpr float ACT_SCALE = 0.1f;
constexpr float EPS       = 1e-6f;

#define VEL_BASE ((size_t)BB * (NSUB + 1) * NV * 3)
#define NBLK ((NV + 255) / 256)        // 391 blocks for per-node arrays
#define PADCAP (2 * NE + 3 * NV + 64)  // padded slot capacity

typedef float fv4 __attribute__((ext_vector_type(4)));
typedef int   iv4 __attribute__((ext_vector_type(4)));

// ---------- one-time setup ----------

// Merged: one thread per gid < BB*NV does state init for (v = gid>>2, b = gid&3)
// AND degree-count for edge gid. The atomic RETURN VALUE is this edge's rank
// among its node's edges -> stored coalesced; the fill needs no atomics at all
// (round-17 lesson: fill was atomic-RMW-latency-bound, not write-BW-bound).
__global__ void init_count(const float* __restrict__ pos0,
                           const float* __restrict__ vel0,
                           const int2* __restrict__ edges,
                           float* __restrict__ out,
                           float4* __restrict__ posT,
                           float4* __restrict__ velT,
                           int* __restrict__ deg,
                           int2* __restrict__ rank) {
    int gid = blockIdx.x * blockDim.x + threadIdx.x;
    if (gid < BB * NV) {
        int b = gid & 3, v = gid >> 2;
        const float* ps = pos0 + ((size_t)b * NV + v) * 3;
        const float* vs = vel0 + ((size_t)b * NV + v) * 3;
        float px = ps[0], py = ps[1], pz = ps[2];
        float vx = vs[0], vy = vs[1], vz = vs[2];
        posT[gid] = make_float4(px, py, pz, 0.f);
        if (velT) velT[gid] = make_float4(vx, vy, vz, 0.f);
        size_t o = ((size_t)(b * (NSUB + 1)) * NV + v) * 3;   // slot 0
        out[o + 0] = px; out[o + 1] = py; out[o + 2] = pz;
        out[VEL_BASE + o + 0] = vx; out[VEL_BASE + o + 1] = vy; out[VEL_BASE + o + 2] = vz;
    }
    if (gid < NE) {
        int2 ed = edges[gid];
        int rx = atomicAdd(&deg[ed.x], 1);
        int ry = atomicAdd(&deg[ed.y], 1);
        rank[gid] = make_int2(rx, ry);
    }
}

__global__ void zero_deg(int* __restrict__ deg) {
    int v = blockIdx.x * blockDim.x + threadIdx.x;
    if (v < NV) deg[v] = 0;
}

// --- 3-phase exclusive scan over PADDED degrees -> offs[NV+1] ---
__device__ __forceinline__ int padded(int d) { return (d + 3) & ~3; }

__global__ void scan_partials(const int* __restrict__ deg, int* __restrict__ bsum) {
    __shared__ int red[256];
    int i = blockIdx.x * 256 + threadIdx.x;
    red[threadIdx.x] = (i < NV) ? padded(deg[i]) : 0;
    __syncthreads();
    for (int off = 128; off > 0; off >>= 1) {
        if (threadIdx.x < off) red[threadIdx.x] += red[threadIdx.x + off];
        __syncthreads();
    }
    if (threadIdx.x == 0) bsum[blockIdx.x] = red[0];
}

__global__ void scan_bsums(int* __restrict__ bsum) {   // NBLK <= 512
    __shared__ int s[512];
    int t = threadIdx.x;
    s[t] = (t < NBLK) ? bsum[t] : 0;
    __syncthreads();
    for (int off = 1; off < 512; off <<= 1) {
        int v = (t >= off) ? s[t - off] : 0;
        __syncthreads();
        s[t] += v;
        __syncthreads();
    }
    if (t < NBLK) bsum[t] = (t == 0) ? 0 : s[t - 1];   // exclusive
}

// writes offs; pads tail slots with zero-contribution self-edges.
__global__ void scan_write(const int* __restrict__ deg, const int* __restrict__ bsum,
                           int* __restrict__ offs,
                           int* __restrict__ lo, float* __restrict__ lre2) {
    __shared__ int s[256];
    int i = blockIdx.x * 256 + threadIdx.x;
    int draw = (i < NV) ? deg[i] : 0;
    int d = padded(draw);
    s[threadIdx.x] = d;
    __syncthreads();
    for (int off = 1; off < 256; off <<= 1) {          // inclusive scan
        int v = (threadIdx.x >= off) ? s[threadIdx.x - off] : 0;
        __syncthreads();
        s[threadIdx.x] += v;
        __syncthreads();
    }
    if (i <= NV - 1) {
        int excl = bsum[blockIdx.x] + s[threadIdx.x] - d;
        offs[i] = excl;
        if (i == NV - 1) offs[NV] = excl + d;
        for (int k = excl + draw; k < excl + d; ++k) {
            lo[k] = i;
            size_t kb = (size_t)(k & ~3) * 4 + (k & 3);
            #pragma unroll
            for (int b = 0; b < BB; ++b) lre2[kb + 4 * b] = 0.f;
        }
    }
}

// ---------- adjacency fill (ATOMIC-FREE: slot = offs[node] + rank) ----------
// lo[k] = other node.
// lre2 chunk-transposed: lre2[(k&~3)*4 + b*4 + (k&3)] = K_SPRING * rest_eff[b]
__global__ void fill_rank(const int2* __restrict__ edges,
                          const int2* __restrict__ rank,
                          const int* __restrict__ offs,
                          const float* __restrict__ action,
                          const float* __restrict__ rest_len,
                          int* __restrict__ lo,
                          float* __restrict__ lre2) {
    int e = blockIdx.x * blockDim.x + threadIdx.x;
    if (e >= NE) return;
    int2 ed = edges[e];
    int2 rk = rank[e];
    float krl = K_SPRING * rest_len[e];
    fv4 re;
    #pragma unroll
    for (int b = 0; b < BB; ++b)
        re[b] = krl * (1.0f + ACT_SCALE * tanhf(action[b * NE + e]));
    int p = offs[ed.x] + rk.x;
    int q = offs[ed.y] + rk.y;
    lo[p] = ed.y; lo[q] = ed.x;
    size_t pb = (size_t)(p & ~3) * 4 + (p & 3);
    size_t qb = (size_t)(q & ~3) * 4 + (q & 3);
    #pragma unroll
    for (int b = 0; b < BB; ++b) {
        lre2[pb + 4 * b] = re[b];
        lre2[qb + 4 * b] = re[b];
    }
}

// ---------- per-substep fused gather + integrate (2-way k-split; best measured) ----------
// Thread gid -> (v = gid>>3, h = (gid>>2)&1, b = gid&3). Lanes of one (v,h)
// cover b=0..3 so each neighbor gather is one fully-used 64B line. Each half
// h processes half the node's 4-chunks; halves combine via __shfl_xor(.,4)
// and lane h==0 integrates.
// Lists (lo/lre2) are CACHED loads (re-read 10x; NT loads cost 10x HBM —
// round-13/14 lesson). Trajectory stores NT (round-16 config, best measured;
// round-17 probe: cached vs NT traj stores are within noise).
// coef = K*(len-re)/len == K - (K*re)*rsqrt(d2+EPS); lre2 holds K*re.
template <bool VELT>
__global__ void substep_ks(float* __restrict__ out,
                           const float4* __restrict__ posT,
                           float4* __restrict__ posTn,
                           float4* __restrict__ velT,   // thread-owned slot
                           const int* __restrict__ lo,
                           const float* __restrict__ lre2,
                           const int* __restrict__ offs, int s) {
    int gid = blockIdx.x * blockDim.x + threadIdx.x;
    if (gid >= 2 * BB * NV) return;
    int b = gid & 3, h = (gid >> 2) & 1, v = gid >> 3;

    float4 p = posT[v * 4 + b];
    float fx = 0.f, fy = 0.f, fz = 0.f;

    int start = offs[v], end = offs[v + 1];
    int nc0 = ((((end - start) >> 2) + 1) >> 1) << 2;   // first-half slot count
    int k    = h ? (start + nc0) : start;
    int kend = h ? end : (start + nc0);

#define ACC(q, kre) do { \
        float dx = (q).x - p.x, dy = (q).y - p.y, dz = (q).z - p.z; \
        float d2 = fmaf(dx, dx, fmaf(dy, dy, fmaf(dz, dz, EPS))); \
        float rs = rsqrtf(d2); \
        float t  = fmaf(-(kre), rs, K_SPRING); \
        fx = fmaf(t, dx, fx); fy = fmaf(t, dy, fy); fz = fmaf(t, dz, fz); } while (0)

    for (; k + 7 < kend; k += 8) {
        iv4 oA = *(const iv4*)(lo + k);
        iv4 oB = *(const iv4*)(lo + k + 4);
        fv4 rA = *(const fv4*)(lre2 + 4 * (size_t)k + 4 * b);
        fv4 rB = *(const fv4*)(lre2 + 4 * (size_t)(k + 4) + 4 * b);
        float4 qA0 = posT[oA.x * 4 + b];
        float4 qA1 = posT[oA.y * 4 + b];
        float4 qA2 = posT[oA.z * 4 + b];
        float4 qA3 = posT[oA.w * 4 + b];
        float4 qB0 = posT[oB.x * 4 + b];
        float4 qB1 = posT[oB.y * 4 + b];
        float4 qB2 = posT[oB.z * 4 + b];
        float4 qB3 = posT[oB.w * 4 + b];
        ACC(qA0, rA[0]); ACC(qA1, rA[1]); ACC(qA2, rA[2]); ACC(qA3, rA[3]);
        ACC(qB0, rB[0]); ACC(qB1, rB[1]); ACC(qB2, rB[2]); ACC(qB3, rB[3]);
    }
    if (k < kend) {   // one remaining 4-chunk
        iv4 o = *(const iv4*)(lo + k);
        fv4 r = *(const fv4*)(lre2 + 4 * (size_t)k + 4 * b);
        float4 q0 = posT[o.x * 4 + b];
        float4 q1 = posT[o.y * 4 + b];
        float4 q2 = posT[o.z * 4 + b];
        float4 q3 = posT[o.w * 4 + b];
        ACC(q0, r[0]); ACC(q1, r[1]); ACC(q2, r[2]); ACC(q3, r[3]);
    }
#undef ACC

    // combine the two halves (lane ^ 4 flips h)
    fx += __shfl_xor(fx, 4);
    fy += __shfl_xor(fy, 4);
    fz += __shfl_xor(fz, 4);

    if (h == 0) {
        int tg = v * 4 + b;   // (v,b) slot in posT/velT
        size_t cur = ((size_t)(b * (NSUB + 1) + s)) * NV * 3 + (size_t)v * 3;
        size_t nxt = cur + (size_t)NV * 3;

        float vcx, vcy, vcz;
        if (VELT) {
            float4 vc = velT[tg];
            vcx = vc.x; vcy = vc.y; vcz = vc.z;
        } else {
            vcx = out[VEL_BASE + cur + 0];
            vcy = out[VEL_BASE + cur + 1];
            vcz = out[VEL_BASE + cur + 2];
        }
        float vx = (vcx + DT * fx) * DAMP;
        float vy = (vcy + DT * (fy - 9.8f)) * DAMP;
        float vz = (vcz + DT * fz) * DAMP;
        float pxn = p.x + DT * vx, pyn = p.y + DT * vy, pzn = p.z + DT * vz;

        __builtin_nontemporal_store(pxn, out + nxt + 0);
        __builtin_nontemporal_store(pyn, out + nxt + 1);
        __builtin_nontemporal_store(pzn, out + nxt + 2);
        if (VELT) {
            __builtin_nontemporal_store(vx, out + VEL_BASE + nxt + 0);
            __builtin_nontemporal_store(vy, out + VEL_BASE + nxt + 1);
            __builtin_nontemporal_store(vz, out + VEL_BASE + nxt + 2);
            velT[tg] = make_float4(vx, vy, vz, 0.f);
        } else {
            out[VEL_BASE + nxt + 0] = vx;
            out[VEL_BASE + nxt + 1] = vy;
            out[VEL_BASE + nxt + 2] = vz;
        }
        posTn[tg] = make_float4(pxn, pyn, pzn, 0.f);
    }
}

extern "C" void kernel_launch(void* const* d_in, const int* in_sizes, int n_in,
                              void* d_out, int out_size, void* d_ws, size_t ws_size,
                              hipStream_t stream) {
    const float* action   = (const float*)d_in[0];
    const float* pos0     = (const float*)d_in[1];
    const float* vel0     = (const float*)d_in[2];
    const float* rest_len = (const float*)d_in[3];
    const int2*  edges    = (const int2*)d_in[4];
    float* out = (float*)d_out;

    // workspace layout (ws_size >= ~56 MB confirmed: round-15 two-phase ran)
    char* ws = (char*)d_ws;
    size_t off = 0;
    int* deg    = (int*)(ws + off); off += (size_t)NV * 4;
    int* offs   = (int*)(ws + off); off += (size_t)(NV + 1) * 4;
    int* bsum   = (int*)(ws + off); off += (size_t)(NBLK + 4) * 4;
    off = (off + 63) & ~(size_t)63;
    float4* pTa = (float4*)(ws + off); off += (size_t)NV * BB * 16;  // 6.4 MB
    float4* pTb = (float4*)(ws + off); off += (size_t)NV * BB * 16;  // 6.4 MB
    int*   lo   = (int*)(ws + off);   off += (size_t)PADCAP * 4;     // 4.4 MB
    float* lre2 = (float*)(ws + off); off += (size_t)PADCAP * 16;    // 17.6 MB
    int2*  rank = (int2*)(ws + off);  off += (size_t)NE * 8;         // 3.2 MB
    float4* vT = (float4*)(ws + off);
    const bool velt = ws_size >= off + (size_t)NV * BB * 16;         // +6.4 MB -> ~45.7 MB total

    const int nBV = BB * NV;
    const int nKS = 2 * BB * NV;   // 2-way k-split thread count
    const int nIC = (nBV > NE ? nBV : NE);

    zero_deg<<<NBLK, 256, 0, stream>>>(deg);
    init_count<<<(nIC + 255) / 256, 256, 0, stream>>>(pos0, vel0, edges, out, pTa,
                                                      velt ? vT : nullptr, deg, rank);
    scan_partials<<<NBLK, 256, 0, stream>>>(deg, bsum);
    scan_bsums<<<1, 512, 0, stream>>>(bsum);
    scan_write<<<NBLK, 256, 0, stream>>>(deg, bsum, offs, lo, lre2);
    fill_rank<<<(NE + 255) / 256, 256, 0, stream>>>(edges, rank, offs, action,
                                                    rest_len, lo, lre2);

    for (int s = 0; s < NSUB; ++s) {
        float4* pc = (s & 1) ? pTb : pTa;
        float4* pn = (s & 1) ? pTa : pTb;
        if (velt) {
            substep_ks<true><<<(nKS + 255) / 256, 256, 0, stream>>>(
                out, pc, pn, vT, lo, lre2, offs, s);
        } else {
            substep_ks<false><<<(nKS + 255) / 256, 256, 0, stream>>>(
                out, pc, pn, nullptr, lo, lre2, offs, s);
        }
    }
}